// Round 1
// baseline (619.621 us; speedup 1.0000x reference)
//
#include <hip/hip_runtime.h>
#include <math.h>

namespace {
constexpr int NB   = 16;
constexpr int NC   = 684;
constexpr int NH   = 32;
constexpr int NW   = 128;
constexpr int NHID = 256;
constexpr int NA   = 512;
constexpr int HW   = NH * NW;  // 4096
}

__device__ __forceinline__ float fast_tanh(float x) {
  // 1 - 2/(e^{2x}+1): safe at both saturation ends (no inf/inf)
  float e = __expf(2.0f * x);
  return 1.0f - 2.0f / (e + 1.0f);
}

// query[b,a] = b_hidden[a] + hidden[b,:] . W_hidden[a,:]
__global__ __launch_bounds__(512) void query_kernel(
    const float* __restrict__ hidden, const float* __restrict__ Wh,
    const float* __restrict__ bh, float* __restrict__ q) {
  const int b = blockIdx.x, a = threadIdx.x;
  const float4* h4 = reinterpret_cast<const float4*>(hidden + b * NHID);
  const float4* w4 = reinterpret_cast<const float4*>(Wh + (size_t)a * NHID);
  float s = bh[a];
  #pragma unroll 8
  for (int k = 0; k < NHID / 4; ++k) {
    float4 hv = h4[k], wv = w4[k];
    s = fmaf(hv.x, wv.x, s); s = fmaf(hv.y, wv.y, s);
    s = fmaf(hv.z, wv.z, s); s = fmaf(hv.w, wv.w, s);
  }
  q[b * NA + a] = s;
}

// M[a][dy*12+dx] = sum_k W_attn[a,k] * Wc[k, dy*11+dx]   (dx==11 is zero pad)
__global__ __launch_bounds__(192) void m_kernel(
    const float* __restrict__ Wattn, const float* __restrict__ Wc,
    float* __restrict__ M) {
  const int a = blockIdx.x, t = threadIdx.x;
  if (t >= 132) return;
  const int dy = t / 12, dx = t % 12;
  float s = 0.0f;
  if (dx < 11) {
    const int j = dy * 11 + dx;
    const float* wa = Wattn + (size_t)a * 512;
    for (int k = 0; k < 512; ++k) s = fmaf(wa[k], Wc[k * 121 + j], s);
  }
  M[(size_t)a * 132 + t] = s;
}

// energy[b,h,w] = sum_a W_alpha[a] * tanh(q[b,a] + cov[b,h,w,a] + cft[b,a,h,w] + cmt[b,h,w,a])
__global__ __launch_bounds__(256) void energy_kernel(
    const float* __restrict__ cft,   // [B,A,H,W]
    const float* __restrict__ cmt,   // [B,H,W,A]
    const float* __restrict__ asum,  // [B,1,H,W]
    const float* __restrict__ q,     // [B,A]
    const float* __restrict__ M,     // [A,132]
    const float* __restrict__ walpha,// [A]
    float* __restrict__ energy)      // [B,H*W]
{
  const int blk  = blockIdx.x;       // B*H = 512
  const int b    = blk >> 5;
  const int h    = blk & 31;
  const int tid  = threadIdx.x;
  const int lane = tid & 63;
  const int wave = __builtin_amdgcn_readfirstlane(tid >> 6);  // 0..3, a-chunk

  __shared__ float asum_lds[11][144];        // rows h-5..h+5, cols -5..132 (zero pad)
  __shared__ float cmt_lds[4][16][NW];       // per-wave [a_local][w]
  __shared__ float part[4][NW];

  for (int i = tid; i < 11 * 144; i += 256) {
    const int r = i / 144, cc = i % 144;
    const int y = h + r - 5, x = cc - 5;
    float v = 0.0f;
    if (y >= 0 && y < NH && x >= 0 && x < NW) v = asum[(b * NH + y) * NW + x];
    asum_lds[r][cc] = v;
  }
  __syncthreads();

  const int w0 = lane, w1 = lane + 64;
  float acc0 = 0.0f, acc1 = 0.0f;
  const int abase = wave * 128;
  const float* cmt_base = cmt + (size_t)(b * NH + h) * NW * NA;
  const float* q_b = q + b * NA;
  const int wl = lane >> 2;          // 0..15
  const int a4 = (lane & 3) << 2;    // 0,4,8,12

  for (int ab = 0; ab < 8; ++ab) {
    const int a16 = abase + ab * 16;

    // stage cmt[w][a16..a16+15] -> cmt_lds[wave][a][w] (coalesced 64B rows per 16 w)
    #pragma unroll
    for (int p = 0; p < 8; ++p) {
      const int w = p * 16 + wl;
      const float4 v = *reinterpret_cast<const float4*>(
          cmt_base + (size_t)w * NA + (a16 + a4));
      cmt_lds[wave][a4 + 0][w] = v.x;
      cmt_lds[wave][a4 + 1][w] = v.y;
      cmt_lds[wave][a4 + 2][w] = v.z;
      cmt_lds[wave][a4 + 3][w] = v.w;
    }
    // same-wave producer/consumer on private region: compiler orders via lgkmcnt

    float cov0[16], cov1[16];
    #pragma unroll
    for (int i = 0; i < 16; ++i) { cov0[i] = 0.0f; cov1[i] = 0.0f; }

    for (int dy = 0; dy < 11; ++dy) {
      float p0[11], p1[11];
      #pragma unroll
      for (int dx = 0; dx < 11; ++dx) {
        p0[dx] = asum_lds[dy][w0 + dx];
        p1[dx] = asum_lds[dy][w1 + dx];
      }
      #pragma unroll
      for (int ai = 0; ai < 16; ++ai) {
        const float4* mr = reinterpret_cast<const float4*>(
            M + (size_t)(a16 + ai) * 132 + dy * 12);
        const float4 m0 = mr[0];
        const float4 m1 = mr[1];
        const float4 m2 = mr[2];
        float c0 = cov0[ai], c1 = cov1[ai];
        c0 = fmaf(p0[0], m0.x, c0);  c1 = fmaf(p1[0], m0.x, c1);
        c0 = fmaf(p0[1], m0.y, c0);  c1 = fmaf(p1[1], m0.y, c1);
        c0 = fmaf(p0[2], m0.z, c0);  c1 = fmaf(p1[2], m0.z, c1);
        c0 = fmaf(p0[3], m0.w, c0);  c1 = fmaf(p1[3], m0.w, c1);
        c0 = fmaf(p0[4], m1.x, c0);  c1 = fmaf(p1[4], m1.x, c1);
        c0 = fmaf(p0[5], m1.y, c0);  c1 = fmaf(p1[5], m1.y, c1);
        c0 = fmaf(p0[6], m1.z, c0);  c1 = fmaf(p1[6], m1.z, c1);
        c0 = fmaf(p0[7], m1.w, c0);  c1 = fmaf(p1[7], m1.w, c1);
        c0 = fmaf(p0[8], m2.x, c0);  c1 = fmaf(p1[8], m2.x, c1);
        c0 = fmaf(p0[9], m2.y, c0);  c1 = fmaf(p1[9], m2.y, c1);
        c0 = fmaf(p0[10], m2.z, c0); c1 = fmaf(p1[10], m2.z, c1);
        cov0[ai] = c0; cov1[ai] = c1;
      }
    }

    #pragma unroll
    for (int ai = 0; ai < 16; ++ai) {
      const int a = a16 + ai;
      const float qa = q_b[a];       // wave-uniform -> s_load
      const float wa = walpha[a];    // wave-uniform
      const float* cr = cft + ((size_t)(b * NA + a) * NH + h) * NW;
      const float e0 = qa + cov0[ai] + cr[w0] + cmt_lds[wave][ai][w0];
      const float e1 = qa + cov1[ai] + cr[w1] + cmt_lds[wave][ai][w1];
      acc0 = fmaf(wa, fast_tanh(e0), acc0);
      acc1 = fmaf(wa, fast_tanh(e1), acc1);
    }
  }

  part[wave][w0] = acc0;
  part[wave][w1] = acc1;
  __syncthreads();
  if (tid < NW) {
    energy[(b * NH + h) * NW + tid] =
        part[0][tid] + part[1][tid] + part[2][tid] + part[3][tid];
  }
}

// per-b softmax over 4096 (mask-aware); writes alpha in place over energy, plus alpha_sum_new
__global__ __launch_bounds__(256) void softmax_kernel(
    float* __restrict__ energy_alpha,      // [B,4096] in, alpha out (same buffer)
    const int* __restrict__ mask,          // [B,4096]
    const float* __restrict__ asum,        // [B,4096]
    float* __restrict__ asum_new)          // [B,4096]
{
  const int b = blockIdx.x, tid = threadIdx.x;
  const int base = b * HW;
  __shared__ float redm[4];
  __shared__ float reds[4];

  float mx = -1e30f;
  for (int i = tid; i < HW; i += 256) {
    float e = energy_alpha[base + i];
    e = mask[base + i] ? e : -1e30f;
    mx = fmaxf(mx, e);
  }
  #pragma unroll
  for (int o = 32; o > 0; o >>= 1) mx = fmaxf(mx, __shfl_down(mx, o));
  if ((tid & 63) == 0) redm[tid >> 6] = mx;
  __syncthreads();
  mx = fmaxf(fmaxf(redm[0], redm[1]), fmaxf(redm[2], redm[3]));

  float s = 0.0f;
  for (int i = tid; i < HW; i += 256) {
    const float e = energy_alpha[base + i];
    s += mask[base + i] ? expf(e - mx) : 0.0f;
  }
  #pragma unroll
  for (int o = 32; o > 0; o >>= 1) s += __shfl_down(s, o);
  if ((tid & 63) == 0) reds[tid >> 6] = s;
  __syncthreads();
  s = reds[0] + reds[1] + reds[2] + reds[3];
  const float inv = 1.0f / s;

  for (int i = tid; i < HW; i += 256) {
    const float e = energy_alpha[base + i];
    const float a = mask[base + i] ? expf(e - mx) * inv : 0.0f;
    energy_alpha[base + i] = a;
    asum_new[base + i] = a + asum[base + i];
  }
}

// context[b,c] = sum_i alpha[b,i] * cnn[b,c,i]
__global__ __launch_bounds__(256) void context_kernel(
    const float* __restrict__ cnn, const float* __restrict__ alpha,
    float* __restrict__ out) {
  const int blk = blockIdx.x;            // NB*NC
  const int b = blk / NC, c = blk - b * NC;
  const float4* crow = reinterpret_cast<const float4*>(cnn + (size_t)(b * NC + c) * HW);
  const float4* arow = reinterpret_cast<const float4*>(alpha + (size_t)b * HW);
  const int tid = threadIdx.x;
  float s = 0.0f;
  #pragma unroll
  for (int i = tid; i < HW / 4; i += 256) {
    const float4 cv = crow[i];
    const float4 av = arow[i];
    s = fmaf(cv.x, av.x, s); s = fmaf(cv.y, av.y, s);
    s = fmaf(cv.z, av.z, s); s = fmaf(cv.w, av.w, s);
  }
  #pragma unroll
  for (int o = 32; o > 0; o >>= 1) s += __shfl_down(s, o);
  __shared__ float red[4];
  if ((tid & 63) == 0) red[tid >> 6] = s;
  __syncthreads();
  if (tid == 0) out[blk] = red[0] + red[1] + red[2] + red[3];
}

extern "C" void kernel_launch(void* const* d_in, const int* in_sizes, int n_in,
                              void* d_out, int out_size, void* d_ws, size_t ws_size,
                              hipStream_t stream) {
  const float* cnn    = (const float*)d_in[0];   // [16,684,32,128]
  const float* cft    = (const float*)d_in[1];   // [16,512,32,128]
  const float* hidden = (const float*)d_in[2];   // [16,256]
  const float* asum   = (const float*)d_in[3];   // [16,1,32,128]
  const int*   mask   = (const int*)  d_in[4];   // [16,1,32,128]
  const float* cmt    = (const float*)d_in[5];   // [16,32,128,512]
  const float* Wh     = (const float*)d_in[6];   // [512,256]
  const float* bh     = (const float*)d_in[7];   // [512]
  const float* Wc     = (const float*)d_in[8];   // [512,1,11,11]
  const float* Wattn  = (const float*)d_in[9];   // [512,512]
  const float* Walpha = (const float*)d_in[10];  // [1,512]
  // d_in[11] = b_alpha: constant shift, cancels in softmax

  float* out_ctx   = (float*)d_out;              // [16,684]
  float* out_alpha = out_ctx + NB * NC;          // [16,4096] (energy scratch, then alpha)
  float* out_asum  = out_alpha + NB * HW;        // [16,4096]

  float* ws_q = (float*)d_ws;                    // 16*512
  float* ws_M = ws_q + NB * NA;                  // 512*132

  query_kernel<<<NB, 512, 0, stream>>>(hidden, Wh, bh, ws_q);
  m_kernel<<<NA, 192, 0, stream>>>(Wattn, Wc, ws_M);
  energy_kernel<<<NB * NH, 256, 0, stream>>>(cft, cmt, asum, ws_q, ws_M, Walpha, out_alpha);
  softmax_kernel<<<NB, 256, 0, stream>>>(out_alpha, mask, asum, out_asum);
  context_kernel<<<NB * NC, 256, 0, stream>>>(cnn, out_alpha, out_ctx);
}